// Round 9
// baseline (652.947 us; speedup 1.0000x reference)
//
#include <hip/hip_runtime.h>
#include <stdint.h>

#define SCALE 0.04419417382415922f  // 1/sqrt(512)

typedef __bf16 bf16x8 __attribute__((ext_vector_type(8)));
typedef float f32x4 __attribute__((ext_vector_type(4)));
typedef uint16_t u16x8 __attribute__((ext_vector_type(8)));

static __device__ __forceinline__ uint16_t f2bf(float f) {
  union { float f; uint32_t u; } v; v.f = f;
  uint32_t u = v.u;
  return (uint16_t)((u + 0x7FFFu + ((u >> 16) & 1u)) >> 16);
}
static __device__ __forceinline__ float bf2f(uint16_t h) {
  union { uint32_t u; float f; } v; v.u = ((uint32_t)h) << 16;
  return v.f;
}

static __device__ __forceinline__ void gload16(const void* g, void* l) {
  __builtin_amdgcn_global_load_lds(
      (__attribute__((address_space(1))) void*)g,
      (__attribute__((address_space(3))) void*)l, 16, 0, 0);
}

#define P_BAR asm volatile("s_barrier" ::: "memory")
#define P_LGKM do { asm volatile("s_waitcnt lgkmcnt(0)" ::: "memory"); \
                    __builtin_amdgcn_sched_barrier(0); } while (0)

// ---------------- conversions / packing (R5/R6-verified) ----------------

__global__ __launch_bounds__(256)
void convert_x(const float* __restrict__ x, uint16_t* __restrict__ xb) {
  size_t i = ((size_t)blockIdx.x * 256 + threadIdx.x) * 8;
  float4 a = *(const float4*)(x + i);
  float4 b = *(const float4*)(x + i + 4);
  u16x8 o;
  o[0] = f2bf(a.x); o[1] = f2bf(a.y); o[2] = f2bf(a.z); o[3] = f2bf(a.w);
  o[4] = f2bf(b.x); o[5] = f2bf(b.y); o[6] = f2bf(b.z); o[7] = f2bf(b.w);
  *(u16x8*)(xb + i) = o;
}

__global__ __launch_bounds__(256)
void pack_wraw(const float* __restrict__ Wq, const float* __restrict__ Wk,
               const float* __restrict__ Wv,
               uint16_t* __restrict__ oq, uint16_t* __restrict__ ok,
               uint16_t* __restrict__ ov) {
  size_t i = ((size_t)blockIdx.x * 256 + threadIdx.x) * 8;
  const int m = blockIdx.y;
  const float* src = (m == 0) ? Wq : ((m == 1) ? Wk : Wv);
  uint16_t* dst = (m == 0) ? oq : ((m == 1) ? ok : ov);
  const float scl = (m == 0) ? SCALE : 1.0f;
  float4 a = *(const float4*)(src + i);
  float4 b = *(const float4*)(src + i + 4);
  u16x8 o;
  o[0] = f2bf(a.x * scl); o[1] = f2bf(a.y * scl);
  o[2] = f2bf(a.z * scl); o[3] = f2bf(a.w * scl);
  o[4] = f2bf(b.x * scl); o[5] = f2bf(b.y * scl);
  o[6] = f2bf(b.z * scl); o[7] = f2bf(b.w * scl);
  *(u16x8*)(dst + i) = o;
}

__global__ __launch_bounds__(256)
void pack_wo(const float* __restrict__ Wo, uint16_t* __restrict__ woT) {
  __shared__ float tile[64][65];
  const int k0 = blockIdx.x * 64, n0 = blockIdx.y * 64;
  const int t = threadIdx.x, r = t >> 2, c0 = (t & 3) * 16;
  float av[16];
  #pragma unroll
  for (int e = 0; e < 16; e++) av[e] = 0.f;
  for (int h = 0; h < 8; h++) {
    const float* src = &Wo[(size_t)(h * 512 + k0 + r) * 512 + n0 + c0];
    #pragma unroll
    for (int j = 0; j < 4; j++) {
      float4 v = *(const float4*)(src + j * 4);
      av[j * 4 + 0] += v.x; av[j * 4 + 1] += v.y;
      av[j * 4 + 2] += v.z; av[j * 4 + 3] += v.w;
    }
  }
  #pragma unroll
  for (int e = 0; e < 16; e++) tile[r][c0 + e] = av[e];
  __syncthreads();
  u16x8 o0, o1;
  #pragma unroll
  for (int e = 0; e < 8; e++) {
    o0[e] = f2bf(tile[c0 + e][r]);
    o1[e] = f2bf(tile[c0 + 8 + e][r]);
  }
  uint16_t* dst = woT + (size_t)(n0 + r) * 512 + k0 + c0;
  *(u16x8*)dst = o0;
  *(u16x8*)(dst + 8) = o1;
}

__global__ __launch_bounds__(256)
void gemv_g(const float* __restrict__ Wk, const float* __restrict__ bq,
            float* __restrict__ g) {
  __shared__ float vs[512];
  const int t = threadIdx.x;
  vs[t] = bq[t]; vs[t + 256] = bq[t + 256];
  __syncthreads();
  const int r = blockIdx.x * 32 + (t >> 3), j = t & 7;
  const float4* p = (const float4*)(Wk + (size_t)r * 512 + j * 64);
  float s = 0.f;
  #pragma unroll
  for (int q = 0; q < 16; q++) {
    float4 v = p[q];
    const float* b = &vs[j * 64 + q * 4];
    s += v.x * b[0] + v.y * b[1] + v.z * b[2] + v.w * b[3];
  }
  s += __shfl_xor(s, 1); s += __shfl_xor(s, 2); s += __shfl_xor(s, 4);
  if (j == 0) g[r] = s * SCALE;
}

__global__ __launch_bounds__(256)
void kappa_calc(const float* __restrict__ bq, const float* __restrict__ bk,
                float* __restrict__ g) {
  const int t = threadIdx.x;
  float s = bq[t] * bk[t] + bq[t + 256] * bk[t + 256];
  #pragma unroll
  for (int o = 32; o; o >>= 1) s += __shfl_xor(s, o);
  __shared__ float rr[4];
  if ((t & 63) == 0) rr[t >> 6] = s;
  __syncthreads();
  if (t == 0) g[512] = (rr[0] + rr[1] + rr[2] + rr[3]) * SCALE;
}

__global__ __launch_bounds__(256)
void gemv_bvo(const uint16_t* __restrict__ woT, const float* __restrict__ bv,
              float* __restrict__ out) {
  __shared__ float vs[512];
  const int t = threadIdx.x;
  vs[t] = bv[t]; vs[t + 256] = bv[t + 256];
  __syncthreads();
  const int r = blockIdx.x * 32 + (t >> 3), j = t & 7;
  const u16x8* p = (const u16x8*)(woT + (size_t)r * 512 + j * 64);
  float s = 0.f;
  #pragma unroll
  for (int q = 0; q < 8; q++) {
    u16x8 v = p[q];
    #pragma unroll
    for (int e = 0; e < 8; e++) s += bf2f(v[e]) * vs[j * 64 + q * 8 + e];
  }
  s += __shfl_xor(s, 1); s += __shfl_xor(s, 2); s += __shfl_xor(s, 4);
  if (j == 0) out[r] = s;
}

__global__ __launch_bounds__(256)
void c_vec(const uint16_t* __restrict__ xb, const float* __restrict__ g,
           float* __restrict__ cv) {
  __shared__ float gs[513];
  const int t = threadIdx.x;
  for (int i = t; i < 513; i += 256) gs[i] = g[i];
  __syncthreads();
  const int r = blockIdx.x * 32 + (t >> 3);
  const int j = t & 7;
  const uint16_t* p = xb + (size_t)r * 512 + j * 64;
  float s = 0.f;
  #pragma unroll
  for (int q = 0; q < 8; q++) {
    u16x8 v = *(const u16x8*)(p + q * 8);
    #pragma unroll
    for (int e = 0; e < 8; e++) s += bf2f(v[e]) * gs[j * 64 + q * 8 + e];
  }
  s += __shfl_xor(s, 1); s += __shfl_xor(s, 2); s += __shfl_xor(s, 4);
  if (j == 0) cv[r] = s + gs[512];
}

__global__ __launch_bounds__(256)
void transpose_v(const uint16_t* __restrict__ yv, uint16_t* __restrict__ Vt) {
  __shared__ uint16_t tile[64][72];
  const int s0 = blockIdx.x * 64, d0 = blockIdx.y * 64, b = blockIdx.z;
  const int t = threadIdx.x, r = t >> 2, c0 = (t & 3) * 16;
  const uint16_t* src = yv + ((size_t)(b * 4096 + s0 + r)) * 1024 + 512 + d0 + c0;
  *(u16x8*)&tile[r][c0] = *(const u16x8*)src;
  *(u16x8*)&tile[r][c0 + 8] = *(const u16x8*)(src + 8);
  __syncthreads();
  u16x8 o0, o1;
  #pragma unroll
  for (int e = 0; e < 8; e++) { o0[e] = tile[c0 + e][r]; o1[e] = tile[c0 + 8 + e][r]; }
  uint16_t* dst = Vt + ((size_t)b * 512 + d0 + r) * 4096 + s0 + c0;
  *(u16x8*)dst = o0;
  *(u16x8*)(dst + 8) = o1;
}

// =================== 256x{256|128} 8-phase GEMM body (R3-verified) ===================
template<int BN, int MODE>
static __device__ __forceinline__
void gemm8_body(const uint16_t* __restrict__ A, const uint16_t* __restrict__ Bt,
                const float* __restrict__ bias, void* __restrict__ Cout,
                int M, int N, int K, int lda, int ldb, int ldc) {
  constexpr int NREP = BN / 64;
  constexpr int NH = NREP / 2;
  constexpr int WN = BN / 4;
  constexpr int BELTS = BN * 64;
  __shared__ uint16_t SH[32768 + 2 * BELTS];

  const int nbn = N / BN;
  const int nwg = (M >> 8) * nbn;
  int id = blockIdx.x;
  id = (id & 7) * (nwg >> 3) + (id >> 3);
  const int bm = id / nbn, bn = id % nbn;
  const size_t m0 = (size_t)bm * 256, n0 = (size_t)bn * BN;

  const int t = threadIdx.x;
  const int lane = t & 63, w = t >> 6;
  const int wr = w >> 2, wc = w & 3;
  const int l15 = lane & 15, l4 = lane >> 4, l7 = lane & 7, l3 = lane >> 3;
  const int sw = l7 ^ l3;

  const uint16_t* srcA = A + (m0 + w * 8 + l3) * (size_t)lda + sw * 8;
  const uint16_t* srcB = (BN == 256)
      ? Bt + (n0 + (w >> 1) * 64 + (w & 1) * 16 + l3) * (size_t)ldb + sw * 8
      : Bt + (n0 + (w >> 1) * 32 + (w & 1) * 8 + l3) * (size_t)ldb + sw * 8;

  const int NKT = K >> 6;
  const int NIT = NKT >> 1;

  f32x4 acc[8][NREP];
  #pragma unroll
  for (int i = 0; i < 8; i++)
    #pragma unroll
    for (int j = 0; j < NREP; j++) acc[i][j] = (f32x4)(0.f);

  bf16x8 a[4][2], b0[NH][2], b1[NH][2];

  auto stageA = [&](int tile, int mh) {
    const uint16_t* s = srcA + mh * 64 * (size_t)lda + tile * 64;
    uint16_t* d = SH + (tile & 1) * 16384 + mh * 4096 + w * 512;
    gload16(s, d);
    gload16(s + 128 * (size_t)lda, d + 8192);
  };
  auto stageB = [&](int tile, int nh) {
    if (BN == 256) {
      const uint16_t* s = srcB + nh * 32 * (size_t)ldb + tile * 64;
      uint16_t* d = SH + 32768 + (tile & 1) * BELTS + (w >> 1) * 4096 + nh * 2048 + (w & 1) * 1024;
      gload16(s, d);
      gload16(s + 8 * (size_t)ldb, d + 512);
    } else {
      const uint16_t* s = srcB + nh * 16 * (size_t)ldb + tile * 64;
      uint16_t* d = SH + 32768 + (tile & 1) * BELTS + (w >> 1) * 2048 + nh * 1024 + (w & 1) * 512;
      gload16(s, d);
    }
  };
  auto loadA = [&](int buf, int mh) {
    const uint16_t* base = SH + buf * 16384 + (wr * 128 + mh * 64 + l15) * 64;
    #pragma unroll
    for (int m = 0; m < 4; m++)
      #pragma unroll
      for (int ks = 0; ks < 2; ks++)
        a[m][ks] = *(const bf16x8*)(base + m * 1024 + (((ks * 4 + l4) ^ l7) * 8));
  };
  auto loadB = [&](int buf, int nh, bf16x8 (&bd)[NH][2]) {
    const uint16_t* base = SH + 32768 + buf * BELTS + (wc * WN + nh * (WN / 2) + l15) * 64;
    #pragma unroll
    for (int n = 0; n < NH; n++)
      #pragma unroll
      for (int ks = 0; ks < 2; ks++)
        bd[n][ks] = *(const bf16x8*)(base + n * 1024 + (((ks * 4 + l4) ^ l7) * 8));
  };
  auto quad = [&](int mh, int nq, bf16x8 (&bq)[NH][2]) {
    __builtin_amdgcn_s_setprio(1);
    #pragma unroll
    for (int m = 0; m < 4; m++)
      #pragma unroll
      for (int n = 0; n < NH; n++)
        #pragma unroll
        for (int ks = 0; ks < 2; ks++)
          acc[mh * 4 + m][nq + n] = __builtin_amdgcn_mfma_f32_16x16x32_bf16(
              a[m][ks], bq[n][ks], acc[mh * 4 + m][nq + n], 0, 0, 0);
    __builtin_amdgcn_s_setprio(0);
  };

  stageA(0, 0); stageB(0, 0); stageA(0, 1); stageB(0, 1);
  stageA(1, 0); stageB(1, 0); stageA(1, 1);
  if (BN == 256) asm volatile("s_waitcnt vmcnt(6)" ::: "memory");
  else           asm volatile("s_waitcnt vmcnt(5)" ::: "memory");
  P_BAR;

  for (int k = 0; k < NIT - 1; ++k) {
    const int tt = 2 * k;
    loadA(0, 0); loadB(0, 0, b0); stageB(tt + 1, 1);
    P_BAR; P_LGKM; quad(0, 0, b0); P_BAR;
    loadB(0, 1, b1); stageA(tt + 2, 0);
    P_BAR; P_LGKM; quad(0, NH, b1); P_BAR;
    loadA(0, 1); stageB(tt + 2, 0);
    P_BAR; P_LGKM; quad(1, NH, b1); P_BAR;
    stageA(tt + 2, 1);
    if (BN == 256) asm volatile("s_waitcnt vmcnt(6)" ::: "memory");
    else           asm volatile("s_waitcnt vmcnt(5)" ::: "memory");
    P_BAR; quad(1, 0, b0); P_BAR;
    loadA(1, 0); loadB(1, 0, b0); stageB(tt + 2, 1);
    P_BAR; P_LGKM; quad(0, 0, b0); P_BAR;
    loadB(1, 1, b1); stageA(tt + 3, 0);
    P_BAR; P_LGKM; quad(0, NH, b1); P_BAR;
    loadA(1, 1); stageB(tt + 3, 0);
    P_BAR; P_LGKM; quad(1, NH, b1); P_BAR;
    stageA(tt + 3, 1);
    if (BN == 256) asm volatile("s_waitcnt vmcnt(6)" ::: "memory");
    else           asm volatile("s_waitcnt vmcnt(5)" ::: "memory");
    P_BAR; quad(1, 0, b0); P_BAR;
  }
  loadA(0, 0); loadB(0, 0, b0); stageB(NKT - 1, 1);
  P_BAR; P_LGKM; quad(0, 0, b0); P_BAR;
  loadB(0, 1, b1);
  P_BAR; P_LGKM; quad(0, NH, b1); P_BAR;
  loadA(0, 1);
  P_BAR; P_LGKM; quad(1, NH, b1); P_BAR;
  asm volatile("s_waitcnt vmcnt(0)" ::: "memory");
  P_BAR; quad(1, 0, b0); P_BAR;
  loadA(1, 0); loadB(1, 0, b0);
  P_BAR; P_LGKM; quad(0, 0, b0); P_BAR;
  loadB(1, 1, b1);
  P_BAR; P_LGKM; quad(0, NH, b1); P_BAR;
  loadA(1, 1);
  P_BAR; P_LGKM; quad(1, NH, b1); P_BAR;
  quad(1, 0, b0);

  asm volatile("s_waitcnt vmcnt(0) lgkmcnt(0)" ::: "memory");
  __syncthreads();

  const int g = l4;
  float bvv[NREP];
  #pragma unroll
  for (int ni = 0; ni < NREP; ni++)
    bvv[ni] = (bias != nullptr) ? bias[n0 + wc * WN + ni * 16 + l15] : 0.f;

  constexpr int STR = BN + 8;
  uint16_t* C16 = (uint16_t*)Cout;
  #pragma unroll
  for (int h = 0; h < 2; ++h) {
    __syncthreads();
    if (wr == h) {
      #pragma unroll
      for (int am = 0; am < 8; am++)
        #pragma unroll
        for (int r = 0; r < 4; r++) {
          const int lr = am * 16 + g * 4 + r;
          #pragma unroll
          for (int ni = 0; ni < NREP; ni++)
            SH[lr * STR + wc * WN + ni * 16 + l15] = f2bf(acc[am][ni][r] + bvv[ni]);
        }
    }
    __syncthreads();
    constexpr int CPT = BN / 32;
    #pragma unroll
    for (int c = 0; c < CPT; ++c) {
      const int idx = t + c * 512;
      const int row = idx / (BN / 8), c8 = idx % (BN / 8);
      *(u16x8*)(C16 + (m0 + h * 128 + row) * (size_t)ldc + n0 + c8 * 8) =
          *(const u16x8*)(SH + row * STR + c8 * 8);
    }
  }
}

__global__ __launch_bounds__(512, 2)
void w2_gemm(const uint16_t* A, const uint16_t* Bt, void* C) {
  gemm8_body<128, 0>(A, Bt, nullptr, C, 512, 512, 512, 512, 512, 512);
}
__global__ __launch_bounds__(512, 2)
void wvo_gemm(const uint16_t* A, const uint16_t* Bt, void* C) {
  gemm8_body<128, 0>(A, Bt, nullptr, C, 512, 512, 512, 512, 512, 512);
}
__global__ __launch_bounds__(512, 2)
void yv_gemm(const uint16_t* A, const uint16_t* Bt, const float* bias, void* C) {
  gemm8_body<256, 0>(A, Bt, bias, C, 16384, 1024, 512, 512, 512, 1024);
}

// =================== fused attention v2: direct-from-L2 fragments ===================
// out = (exp(Y X^T + c) @ VW) * inv + bo. 64 Q-rows/block, kv-tiles of 64.
// Y in regs; X,V fragments loaded straight from L2 (both z-slices are 4 MB, L2-fits;
// z-aware XCD decode keeps them hot). LDS = P bounce only (8 KB). 2 barriers per tile.
__global__ __launch_bounds__(512, 2)
void fa_fused(const uint16_t* __restrict__ yv, const uint16_t* __restrict__ xb,
              const uint16_t* __restrict__ Vt, const float* __restrict__ cv,
              const float* __restrict__ bo, float* __restrict__ out) {
  __shared__ __align__(16) uint16_t SH[4608];  // PL [64 q][64 kv] + pad
  uint16_t* PL = SH;

  // z-aware XCD decode: XCD ~ bid&7; each z pinned to an XCD pair.
  const int bid = blockIdx.x;
  const int xcd = bid & 7;
  const long long z = xcd >> 1;
  const int id = ((bid >> 3) << 1) | (xcd & 1);  // [0,64) within z
  const size_t m0 = (size_t)id * 64;
  const int t = threadIdx.x, lane = t & 63, w = t >> 6;
  const int wr = w >> 2, wc = w & 3;
  const int l15 = lane & 15, l4 = lane >> 4, l7 = lane & 7;

  const uint16_t* Yz = yv + z * (4096ll * 1024);
  const uint16_t* Xz = xb + z * (4096ll * 512);
  const uint16_t* Vz = Vt + z * (512ll * 4096);
  const float*    cz = cv + z * 4096;
  float*          oz = out + z * (4096ll * 512);

  // Y strip resident in registers: a_y[mi][kg], k = kg*32 + l4*8
  bf16x8 a_y[2][16];
  #pragma unroll
  for (int mi = 0; mi < 2; mi++) {
    const uint16_t* yp = Yz + (m0 + wr * 32 + mi * 16 + l15) * 1024 + l4 * 8;
    #pragma unroll
    for (int kg = 0; kg < 16; kg++)
      a_y[mi][kg] = *(const bf16x8*)(yp + kg * 32);
  }

  f32x4 acc[2][8];
  #pragma unroll
  for (int i = 0; i < 2; i++)
    #pragma unroll
    for (int j = 0; j < 8; j++) acc[i][j] = (f32x4)(0.f);
  float ps[2][4];
  #pragma unroll
  for (int i = 0; i < 2; i++)
    #pragma unroll
    for (int r = 0; r < 4; r++) ps[i][r] = 0.f;

  // per-lane row bases for direct fragment loads
  const uint16_t* xrow = Xz + (size_t)(wc * 16 + l15) * 512 + l4 * 8;   // + s0*512 + kg*32
  const uint16_t* vrow0 = Vz + (size_t)(wc * 128 + l15) * 4096 + l4 * 8; // + d*4096 + s0 + ks*32

  #pragma unroll 1
  for (int T = 0; T < 64; ++T) {
    const int s0 = T * 64;

    // ---- S = Y_tile @ X_tile^T : direct global B-frags, 2 halves ----
    f32x4 acc_s[2];
    acc_s[0] = (f32x4)(0.f); acc_s[1] = (f32x4)(0.f);
    const uint16_t* xT = xrow + (size_t)s0 * 512;
    #pragma unroll
    for (int half = 0; half < 2; ++half) {
      bf16x8 bx[8];
      #pragma unroll
      for (int k8 = 0; k8 < 8; k8++)
        bx[k8] = *(const bf16x8*)(xT + (half * 8 + k8) * 32);
      __builtin_amdgcn_s_setprio(1);
      #pragma unroll
      for (int mi = 0; mi < 2; mi++)
        #pragma unroll
        for (int k8 = 0; k8 < 8; k8++)
          acc_s[mi] = __builtin_amdgcn_mfma_f32_16x16x32_bf16(
              a_y[mi][half * 8 + k8], bx[k8], acc_s[mi], 0, 0, 0);
      __builtin_amdgcn_s_setprio(0);
    }

    // ---- exp + P-store (swizzled) + row partials ----
    const float cq = cz[s0 + wc * 16 + l15];
    #pragma unroll
    for (int mi = 0; mi < 2; mi++) {
      const int qb = wr * 32 + mi * 16 + l4 * 4;
      #pragma unroll
      for (int r = 0; r < 4; r++) {
        float p = __expf(acc_s[mi][r] + cq);
        ps[mi][r] += p;
        const int qr = qb + r;
        PL[qr * 64 + (((wc * 2 + (l15 >> 3)) ^ (qr & 7)) * 8) + l7] = f2bf(p);
      }
    }
    __syncthreads();

    // ---- PV: P from LDS, V-frags direct from L2 ----
    bf16x8 pa[2][2];
    #pragma unroll
    for (int m = 0; m < 2; m++)
      #pragma unroll
      for (int ks = 0; ks < 2; ks++)
        pa[m][ks] = *(const bf16x8*)(PL + (wr * 32 + m * 16 + l15) * 64 +
                                     (((ks * 4 + l4) ^ l7) * 8));
    const uint16_t* vT = vrow0 + s0;
    #pragma unroll
    for (int h = 0; h < 2; h++) {
      bf16x8 vb[4][2];
      #pragma unroll
      for (int n = 0; n < 4; n++)
        #pragma unroll
        for (int ks = 0; ks < 2; ks++)
          vb[n][ks] = *(const bf16x8*)(vT + (size_t)((h * 4 + n) * 16) * 4096 + ks * 32);
      __builtin_amdgcn_s_setprio(1);
      #pragma unroll
      for (int m = 0; m < 2; m++)
        #pragma unroll
        for (int n = 0; n < 4; n++)
          #pragma unroll
          for (int ks = 0; ks < 2; ks++)
            acc[m][h * 4 + n] = __builtin_amdgcn_mfma_f32_16x16x32_bf16(
                pa[m][ks], vb[n][ks], acc[m][h * 4 + n], 0, 0, 0);
      __builtin_amdgcn_s_setprio(0);
    }
    __syncthreads();
  }

  // ---- epilogue: row-sum reduce, normalize, +bo, store f32 ----
  float* rs = (float*)SH;  // [4 wc][64 q]
  #pragma unroll
  for (int mi = 0; mi < 2; mi++)
    #pragma unroll
    for (int r = 0; r < 4; r++) {
      float s = ps[mi][r];
      s += __shfl_xor(s, 1); s += __shfl_xor(s, 2);
      s += __shfl_xor(s, 4); s += __shfl_xor(s, 8);
      if (l15 == 0) rs[wc * 64 + wr * 32 + mi * 16 + l4 * 4 + r] = s;
    }
  __syncthreads();
  float inv[2][4];
  #pragma unroll
  for (int mi = 0; mi < 2; mi++)
    #pragma unroll
    for (int r = 0; r < 4; r++) {
      const int q = wr * 32 + mi * 16 + l4 * 4 + r;
      inv[mi][r] = 1.f / (((rs[q] + rs[64 + q]) + (rs[128 + q] + rs[192 + q])));
    }
  float bvv[8];
  #pragma unroll
  for (int n = 0; n < 8; n++) bvv[n] = bo[wc * 128 + n * 16 + l15];
  #pragma unroll
  for (int mi = 0; mi < 2; mi++)
    #pragma unroll
    for (int r = 0; r < 4; r++) {
      float* op = oz + (m0 + wr * 32 + mi * 16 + l4 * 4 + r) * 512 + wc * 128 + l15;
      #pragma unroll
      for (int n = 0; n < 8; n++)
        op[n * 16] = acc[mi][n][r] * inv[mi][r] + bvv[n];
    }
}

// ---------------- launch ----------------

extern "C" void kernel_launch(void* const* d_in, const int* in_sizes, int n_in,
                              void* d_out, int out_size, void* d_ws, size_t ws_size,
                              hipStream_t stream) {
  const float* x   = (const float*)d_in[0];
  const float* Wq  = (const float*)d_in[1];
  const float* bq  = (const float*)d_in[2];
  const float* Wk  = (const float*)d_in[3];
  const float* bk  = (const float*)d_in[4];
  const float* Wv  = (const float*)d_in[5];
  const float* bvp = (const float*)d_in[6];
  const float* Wo  = (const float*)d_in[7];
  const float* bo  = (const float*)d_in[8];
  float* out = (float*)d_out;

  char* ws = (char*)d_ws;
  const size_t MB = (size_t)1 << 20;
  uint16_t* xb   = (uint16_t*)(ws);                         // 16 MB
  uint16_t* yv   = (uint16_t*)(ws + 16 * MB);               // 32 MB (y | VW)
  uint16_t* Vt   = (uint16_t*)(ws + 48 * MB);               // 16 MB (VW^T)
  uint16_t* wqs  = (uint16_t*)(ws + 80 * MB);               // 0.5 MB
  uint16_t* wkr  = (uint16_t*)(ws + 80 * MB + 512 * 1024);  // 0.5 MB
  uint16_t* yvW  = (uint16_t*)(ws + 81 * MB);               // 1 MB: w2T | wvoT
  uint16_t* w2T  = yvW;
  uint16_t* wvoT = yvW + (size_t)512 * 512;
  uint16_t* woT  = (uint16_t*)(ws + 82 * MB);               // 0.5 MB
  uint16_t* wvr  = (uint16_t*)(ws + 82 * MB + 512 * 1024);  // 0.5 MB
  float*    byv  = (float*)   (ws + 83 * MB);               // 4 KB (0 | bvo)
  float*    g    = (float*)   (ws + 83 * MB + 8 * 1024);    // 513 f32
  float*    cv   = (float*)   (ws + 84 * MB);               // 64 KB

  convert_x<<<dim3(4096), dim3(256), 0, stream>>>(x, xb);
  pack_wraw<<<dim3(128, 3), dim3(256), 0, stream>>>(Wq, Wk, Wv, wqs, wkr, wvr);
  pack_wo<<<dim3(8, 8), dim3(256), 0, stream>>>(Wo, woT);
  gemv_g<<<dim3(16), dim3(256), 0, stream>>>(Wk, bq, g);
  kappa_calc<<<dim3(1), dim3(256), 0, stream>>>(bq, bk, g);
  hipMemsetAsync(byv, 0, 512 * sizeof(float), stream);
  gemv_bvo<<<dim3(16), dim3(256), 0, stream>>>(woT, bvp, byv + 512);

  // w2T[n][m] = sum_d Wk[n][d] * (Wq s)[m][d]
  w2_gemm<<<dim3(8, 1, 1), dim3(512), 0, stream>>>(wkr, wqs, w2T);
  // wvoT[n][d] = sum_k woT[n][k] * Wv[d][k]
  wvo_gemm<<<dim3(8, 1, 1), dim3(512), 0, stream>>>(woT, wvr, wvoT);

  // yv = xb @ [w2T; wvoT]^T + [0; bvo]  -> [16384][1024] bf16 (y | VW)
  yv_gemm<<<dim3(256, 1, 1), dim3(512), 0, stream>>>(xb, yvW, byv, yv);

  transpose_v<<<dim3(64, 8, 4), dim3(256), 0, stream>>>(yv, Vt);
  c_vec<<<dim3(512), dim3(256), 0, stream>>>(xb, g, cv);

  // fused attention: out = softmax-normalized exp(Y X^T + c) @ VW + bo
  fa_fused<<<dim3(256, 1, 1), dim3(512), 0, stream>>>(yv, xb, Vt, cv, bo, out);
}

// Round 10
// 258.153 us; speedup vs baseline: 2.5293x; 2.5293x over previous
//
#include <hip/hip_runtime.h>
#include <stdint.h>

#define SCALE 0.04419417382415922f  // 1/sqrt(512)

typedef __bf16 bf16x8 __attribute__((ext_vector_type(8)));
typedef float f32x4 __attribute__((ext_vector_type(4)));
typedef uint16_t u16x8 __attribute__((ext_vector_type(8)));

static __device__ __forceinline__ uint16_t f2bf(float f) {
  union { float f; uint32_t u; } v; v.f = f;
  uint32_t u = v.u;
  return (uint16_t)((u + 0x7FFFu + ((u >> 16) & 1u)) >> 16);
}
static __device__ __forceinline__ float bf2f(uint16_t h) {
  union { uint32_t u; float f; } v; v.u = ((uint32_t)h) << 16;
  return v.f;
}

static __device__ __forceinline__ void gload16(const void* g, void* l) {
  __builtin_amdgcn_global_load_lds(
      (__attribute__((address_space(1))) void*)g,
      (__attribute__((address_space(3))) void*)l, 16, 0, 0);
}

#define P_BAR asm volatile("s_barrier" ::: "memory")
#define P_LGKM do { asm volatile("s_waitcnt lgkmcnt(0)" ::: "memory"); \
                    __builtin_amdgcn_sched_barrier(0); } while (0)

// ---------------- conversions / packing ----------------

__global__ __launch_bounds__(256)
void convert_x(const float* __restrict__ x, uint16_t* __restrict__ xb) {
  size_t i = ((size_t)blockIdx.x * 256 + threadIdx.x) * 8;
  float4 a = *(const float4*)(x + i);
  float4 b = *(const float4*)(x + i + 4);
  u16x8 o;
  o[0] = f2bf(a.x); o[1] = f2bf(a.y); o[2] = f2bf(a.z); o[3] = f2bf(a.w);
  o[4] = f2bf(b.x); o[5] = f2bf(b.y); o[6] = f2bf(b.z); o[7] = f2bf(b.w);
  *(u16x8*)(xb + i) = o;
}

// raw-layout bf16 copies: z=0 Wq*s, z=1 Wk, z=2 Wv
__global__ __launch_bounds__(256)
void pack_wraw(const float* __restrict__ Wq, const float* __restrict__ Wk,
               const float* __restrict__ Wv,
               uint16_t* __restrict__ oq, uint16_t* __restrict__ ok,
               uint16_t* __restrict__ ov) {
  size_t i = ((size_t)blockIdx.x * 256 + threadIdx.x) * 8;
  const int m = blockIdx.y;
  const float* src = (m == 0) ? Wq : ((m == 1) ? Wk : Wv);
  uint16_t* dst = (m == 0) ? oq : ((m == 1) ? ok : ov);
  const float scl = (m == 0) ? SCALE : 1.0f;
  float4 a = *(const float4*)(src + i);
  float4 b = *(const float4*)(src + i + 4);
  u16x8 o;
  o[0] = f2bf(a.x * scl); o[1] = f2bf(a.y * scl);
  o[2] = f2bf(a.z * scl); o[3] = f2bf(a.w * scl);
  o[4] = f2bf(b.x * scl); o[5] = f2bf(b.y * scl);
  o[6] = f2bf(b.z * scl); o[7] = f2bf(b.w * scl);
  *(u16x8*)(dst + i) = o;
}

// woT[n][k] = sum_h Wo[h*512+k][n]
__global__ __launch_bounds__(256)
void pack_wo(const float* __restrict__ Wo, uint16_t* __restrict__ woT) {
  __shared__ float tile[64][65];
  const int k0 = blockIdx.x * 64, n0 = blockIdx.y * 64;
  const int t = threadIdx.x, r = t >> 2, c0 = (t & 3) * 16;
  float av[16];
  #pragma unroll
  for (int e = 0; e < 16; e++) av[e] = 0.f;
  for (int h = 0; h < 8; h++) {
    const float* src = &Wo[(size_t)(h * 512 + k0 + r) * 512 + n0 + c0];
    #pragma unroll
    for (int j = 0; j < 4; j++) {
      float4 v = *(const float4*)(src + j * 4);
      av[j * 4 + 0] += v.x; av[j * 4 + 1] += v.y;
      av[j * 4 + 2] += v.z; av[j * 4 + 3] += v.w;
    }
  }
  #pragma unroll
  for (int e = 0; e < 16; e++) tile[r][c0 + e] = av[e];
  __syncthreads();
  u16x8 o0, o1;
  #pragma unroll
  for (int e = 0; e < 8; e++) {
    o0[e] = f2bf(tile[c0 + e][r]);
    o1[e] = f2bf(tile[c0 + 8 + e][r]);
  }
  uint16_t* dst = woT + (size_t)(n0 + r) * 512 + k0 + c0;
  *(u16x8*)dst = o0;
  *(u16x8*)(dst + 8) = o1;
}

// merged small GEMVs: y=0 -> g[r]=Wk[r,:].bq*s ; y=1 -> byv[r]=0, byv[512+r]=woT[r,:].bv ;
// y=2 (block 0) -> g[512]=kappa
__global__ __launch_bounds__(256)
void gemv_all(const float* __restrict__ Wk, const float* __restrict__ bq,
              const float* __restrict__ bk, const uint16_t* __restrict__ woT,
              const float* __restrict__ bv, float* __restrict__ g,
              float* __restrict__ byv) {
  const int t = threadIdx.x;
  const int mode = blockIdx.y;
  if (mode == 2) {
    if (blockIdx.x != 0) return;
    float s = bq[t] * bk[t] + bq[t + 256] * bk[t + 256];
    #pragma unroll
    for (int o = 32; o; o >>= 1) s += __shfl_xor(s, o);
    __shared__ float rr[4];
    if ((t & 63) == 0) rr[t >> 6] = s;
    __syncthreads();
    if (t == 0) g[512] = (rr[0] + rr[1] + rr[2] + rr[3]) * SCALE;
    return;
  }
  __shared__ float vs[512];
  const float* vec = (mode == 0) ? bq : bv;
  vs[t] = vec[t]; vs[t + 256] = vec[t + 256];
  __syncthreads();
  const int r = blockIdx.x * 32 + (t >> 3), j = t & 7;
  if (mode == 0) {
    const float4* p = (const float4*)(Wk + (size_t)r * 512 + j * 64);
    float s = 0.f;
    #pragma unroll
    for (int q = 0; q < 16; q++) {
      float4 v = p[q];
      const float* b = &vs[j * 64 + q * 4];
      s += v.x * b[0] + v.y * b[1] + v.z * b[2] + v.w * b[3];
    }
    s += __shfl_xor(s, 1); s += __shfl_xor(s, 2); s += __shfl_xor(s, 4);
    if (j == 0) g[r] = s * SCALE;
  } else {
    const u16x8* p = (const u16x8*)(woT + (size_t)r * 512 + j * 64);
    float s = 0.f;
    #pragma unroll
    for (int q = 0; q < 8; q++) {
      u16x8 v = p[q];
      #pragma unroll
      for (int e = 0; e < 8; e++) s += bf2f(v[e]) * vs[j * 64 + q * 8 + e];
    }
    s += __shfl_xor(s, 1); s += __shfl_xor(s, 2); s += __shfl_xor(s, 4);
    if (j == 0) { byv[r] = 0.f; byv[512 + r] = s; }
  }
}

// cv[r] = x_r . g + kappa   (8 lanes per row)
__global__ __launch_bounds__(256)
void c_vec(const uint16_t* __restrict__ xb, const float* __restrict__ g,
           float* __restrict__ cv) {
  __shared__ float gs[513];
  const int t = threadIdx.x;
  for (int i = t; i < 513; i += 256) gs[i] = g[i];
  __syncthreads();
  const int r = blockIdx.x * 32 + (t >> 3);
  const int j = t & 7;
  const uint16_t* p = xb + (size_t)r * 512 + j * 64;
  float s = 0.f;
  #pragma unroll
  for (int q = 0; q < 8; q++) {
    u16x8 v = *(const u16x8*)(p + q * 8);
    #pragma unroll
    for (int e = 0; e < 8; e++) s += bf2f(v[e]) * gs[j * 64 + q * 8 + e];
  }
  s += __shfl_xor(s, 1); s += __shfl_xor(s, 2); s += __shfl_xor(s, 4);
  if (j == 0) cv[r] = s + gs[512];
}

// Vt[b][n][s] = yv[b*4096+s][512+n]   (VW half)
__global__ __launch_bounds__(256)
void transpose_v(const uint16_t* __restrict__ yv, uint16_t* __restrict__ Vt) {
  __shared__ uint16_t tile[64][72];
  const int s0 = blockIdx.x * 64, d0 = blockIdx.y * 64, b = blockIdx.z;
  const int t = threadIdx.x, r = t >> 2, c0 = (t & 3) * 16;
  const uint16_t* src = yv + ((size_t)(b * 4096 + s0 + r)) * 1024 + 512 + d0 + c0;
  *(u16x8*)&tile[r][c0] = *(const u16x8*)src;
  *(u16x8*)&tile[r][c0 + 8] = *(const u16x8*)(src + 8);
  __syncthreads();
  u16x8 o0, o1;
  #pragma unroll
  for (int e = 0; e < 8; e++) { o0[e] = tile[c0 + e][r]; o1[e] = tile[c0 + 8 + e][r]; }
  uint16_t* dst = Vt + ((size_t)b * 512 + d0 + r) * 4096 + s0 + c0;
  *(u16x8*)dst = o0;
  *(u16x8*)(dst + 8) = o1;
}

// =================== 256x{256|128} 8-phase GEMM body (R3/R5/R6-verified) ===================
// MODE 0: bf16 out (+optional bias) | 1: f32 out +bias
// MODE 2: exp(acc + bias_col) -> bf16 + row-sum partials (bias = c-vector, z-strided)
// MODE 4: f32 out * inv[row] + bias (final fused PV+output)
template<int BN, int MODE>
static __device__ __forceinline__
void gemm8_body(const uint16_t* __restrict__ A, const uint16_t* __restrict__ Bt,
                const float* __restrict__ bias, void* __restrict__ Cout,
                const float* __restrict__ sums,
                int M, int N, int K, int lda, int ldb, int ldc,
                long long aZ, long long bZ, long long cZ, long long sZ,
                long long biasZ) {
  constexpr int NREP = BN / 64;
  constexpr int NH = NREP / 2;
  constexpr int WN = BN / 4;
  constexpr int BELTS = BN * 64;
  __shared__ uint16_t SH[32768 + 2 * BELTS];

  const int nbn = N / BN;
  const int nwg = (M >> 8) * nbn;
  int id = blockIdx.x;
  id = (id & 7) * (nwg >> 3) + (id >> 3);
  const int bm = id / nbn, bn = id % nbn;
  const long long z = blockIdx.z;
  A += z * aZ; Bt += z * bZ;
  const size_t m0 = (size_t)bm * 256, n0 = (size_t)bn * BN;

  const int t = threadIdx.x;
  const int lane = t & 63, w = t >> 6;
  const int wr = w >> 2, wc = w & 3;
  const int l15 = lane & 15, l4 = lane >> 4, l7 = lane & 7, l3 = lane >> 3;
  const int sw = l7 ^ l3;

  const uint16_t* srcA = A + (m0 + w * 8 + l3) * (size_t)lda + sw * 8;
  const uint16_t* srcB = (BN == 256)
      ? Bt + (n0 + (w >> 1) * 64 + (w & 1) * 16 + l3) * (size_t)ldb + sw * 8
      : Bt + (n0 + (w >> 1) * 32 + (w & 1) * 8 + l3) * (size_t)ldb + sw * 8;

  const int NKT = K >> 6;
  const int NIT = NKT >> 1;

  f32x4 acc[8][NREP];
  #pragma unroll
  for (int i = 0; i < 8; i++)
    #pragma unroll
    for (int j = 0; j < NREP; j++) acc[i][j] = (f32x4)(0.f);

  bf16x8 a[4][2], b0[NH][2], b1[NH][2];

  auto stageA = [&](int tile, int mh) {
    const uint16_t* s = srcA + mh * 64 * (size_t)lda + tile * 64;
    uint16_t* d = SH + (tile & 1) * 16384 + mh * 4096 + w * 512;
    gload16(s, d);
    gload16(s + 128 * (size_t)lda, d + 8192);
  };
  auto stageB = [&](int tile, int nh) {
    if (BN == 256) {
      const uint16_t* s = srcB + nh * 32 * (size_t)ldb + tile * 64;
      uint16_t* d = SH + 32768 + (tile & 1) * BELTS + (w >> 1) * 4096 + nh * 2048 + (w & 1) * 1024;
      gload16(s, d);
      gload16(s + 8 * (size_t)ldb, d + 512);
    } else {
      const uint16_t* s = srcB + nh * 16 * (size_t)ldb + tile * 64;
      uint16_t* d = SH + 32768 + (tile & 1) * BELTS + (w >> 1) * 2048 + nh * 1024 + (w & 1) * 512;
      gload16(s, d);
    }
  };
  auto loadA = [&](int buf, int mh) {
    const uint16_t* base = SH + buf * 16384 + (wr * 128 + mh * 64 + l15) * 64;
    #pragma unroll
    for (int m = 0; m < 4; m++)
      #pragma unroll
      for (int ks = 0; ks < 2; ks++)
        a[m][ks] = *(const bf16x8*)(base + m * 1024 + (((ks * 4 + l4) ^ l7) * 8));
  };
  auto loadB = [&](int buf, int nh, bf16x8 (&bd)[NH][2]) {
    const uint16_t* base = SH + 32768 + buf * BELTS + (wc * WN + nh * (WN / 2) + l15) * 64;
    #pragma unroll
    for (int n = 0; n < NH; n++)
      #pragma unroll
      for (int ks = 0; ks < 2; ks++)
        bd[n][ks] = *(const bf16x8*)(base + n * 1024 + (((ks * 4 + l4) ^ l7) * 8));
  };
  auto quad = [&](int mh, int nq, bf16x8 (&bq)[NH][2]) {
    __builtin_amdgcn_s_setprio(1);
    #pragma unroll
    for (int m = 0; m < 4; m++)
      #pragma unroll
      for (int n = 0; n < NH; n++)
        #pragma unroll
        for (int ks = 0; ks < 2; ks++)
          acc[mh * 4 + m][nq + n] = __builtin_amdgcn_mfma_f32_16x16x32_bf16(
              a[m][ks], bq[n][ks], acc[mh * 4 + m][nq + n], 0, 0, 0);
    __builtin_amdgcn_s_setprio(0);
  };

  stageA(0, 0); stageB(0, 0); stageA(0, 1); stageB(0, 1);
  stageA(1, 0); stageB(1, 0); stageA(1, 1);
  if (BN == 256) asm volatile("s_waitcnt vmcnt(6)" ::: "memory");
  else           asm volatile("s_waitcnt vmcnt(5)" ::: "memory");
  P_BAR;

  for (int k = 0; k < NIT - 1; ++k) {
    const int tt = 2 * k;
    loadA(0, 0); loadB(0, 0, b0); stageB(tt + 1, 1);
    P_BAR; P_LGKM; quad(0, 0, b0); P_BAR;
    loadB(0, 1, b1); stageA(tt + 2, 0);
    P_BAR; P_LGKM; quad(0, NH, b1); P_BAR;
    loadA(0, 1); stageB(tt + 2, 0);
    P_BAR; P_LGKM; quad(1, NH, b1); P_BAR;
    stageA(tt + 2, 1);
    if (BN == 256) asm volatile("s_waitcnt vmcnt(6)" ::: "memory");
    else           asm volatile("s_waitcnt vmcnt(5)" ::: "memory");
    P_BAR; quad(1, 0, b0); P_BAR;
    loadA(1, 0); loadB(1, 0, b0); stageB(tt + 2, 1);
    P_BAR; P_LGKM; quad(0, 0, b0); P_BAR;
    loadB(1, 1, b1); stageA(tt + 3, 0);
    P_BAR; P_LGKM; quad(0, NH, b1); P_BAR;
    loadA(1, 1); stageB(tt + 3, 0);
    P_BAR; P_LGKM; quad(1, NH, b1); P_BAR;
    stageA(tt + 3, 1);
    if (BN == 256) asm volatile("s_waitcnt vmcnt(6)" ::: "memory");
    else           asm volatile("s_waitcnt vmcnt(5)" ::: "memory");
    P_BAR; quad(1, 0, b0); P_BAR;
  }
  loadA(0, 0); loadB(0, 0, b0); stageB(NKT - 1, 1);
  P_BAR; P_LGKM; quad(0, 0, b0); P_BAR;
  loadB(0, 1, b1);
  P_BAR; P_LGKM; quad(0, NH, b1); P_BAR;
  loadA(0, 1);
  P_BAR; P_LGKM; quad(1, NH, b1); P_BAR;
  asm volatile("s_waitcnt vmcnt(0)" ::: "memory");
  P_BAR; quad(1, 0, b0); P_BAR;
  loadA(1, 0); loadB(1, 0, b0);
  P_BAR; P_LGKM; quad(0, 0, b0); P_BAR;
  loadB(1, 1, b1);
  P_BAR; P_LGKM; quad(0, NH, b1); P_BAR;
  loadA(1, 1);
  P_BAR; P_LGKM; quad(1, NH, b1); P_BAR;
  quad(1, 0, b0);

  asm volatile("s_waitcnt vmcnt(0) lgkmcnt(0)" ::: "memory");
  __syncthreads();

  const int g = l4;

  if (MODE == 1 || MODE == 4) {
    float bvv[NREP];
    #pragma unroll
    for (int ni = 0; ni < NREP; ni++) bvv[ni] = bias[n0 + wc * WN + ni * 16 + l15];
    float4 sc[8];
    if (MODE == 4) {
      #pragma unroll
      for (int am = 0; am < 8; am++)
        sc[am] = *(const float4*)&sums[z * sZ + m0 + wr * 128 + am * 16 + g * 4];
    }
    float* C = (float*)Cout + z * cZ;
    #pragma unroll
    for (int am = 0; am < 8; am++)
      #pragma unroll
      for (int r = 0; r < 4; r++) {
        size_t gr = m0 + wr * 128 + am * 16 + g * 4 + r;
        #pragma unroll
        for (int ni = 0; ni < NREP; ni++) {
          float v = acc[am][ni][r];
          if (MODE == 4) v *= ((const float*)&sc[am])[r];
          C[gr * (size_t)ldc + n0 + wc * WN + ni * 16 + l15] = v + bvv[ni];
        }
      }
    return;
  }

  if (MODE == 2) {  // exp(acc + c_col) + per-(row, 64col) partial sums (BN==256)
    float cvv[NREP];
    #pragma unroll
    for (int ni = 0; ni < NREP; ni++)
      cvv[ni] = bias[z * biasZ + n0 + wc * WN + ni * 16 + l15];
    #pragma unroll
    for (int am = 0; am < 8; am++)
      #pragma unroll
      for (int r = 0; r < 4; r++) {
        float s = 0.f;
        #pragma unroll
        for (int ni = 0; ni < NREP; ni++) {
          float v = __expf(acc[am][ni][r] + cvv[ni]);
          acc[am][ni][r] = v;
          s += v;
        }
        s += __shfl_xor(s, 1); s += __shfl_xor(s, 2);
        s += __shfl_xor(s, 4); s += __shfl_xor(s, 8);
        if (l15 == 0)
          ((float*)sums)[z * sZ + (m0 + wr * 128 + am * 16 + g * 4 + r) * 64 +
                         (n0 >> 6) + wc] = s;
      }
  }

  float bvv[NREP];
  #pragma unroll
  for (int ni = 0; ni < NREP; ni++)
    bvv[ni] = (MODE == 0 && bias) ? bias[n0 + wc * WN + ni * 16 + l15] : 0.f;

  constexpr int STR = BN + 8;
  uint16_t* C16 = (uint16_t*)Cout + z * cZ;
  #pragma unroll
  for (int h = 0; h < 2; ++h) {
    __syncthreads();
    if (wr == h) {
      #pragma unroll
      for (int am = 0; am < 8; am++)
        #pragma unroll
        for (int r = 0; r < 4; r++) {
          const int lr = am * 16 + g * 4 + r;
          #pragma unroll
          for (int ni = 0; ni < NREP; ni++) {
            float v = acc[am][ni][r] + bvv[ni];
            SH[lr * STR + wc * WN + ni * 16 + l15] = f2bf(v);
          }
        }
    }
    __syncthreads();
    constexpr int CPT = BN / 32;
    #pragma unroll
    for (int c = 0; c < CPT; ++c) {
      const int idx = t + c * 512;
      const int row = idx / (BN / 8), c8 = idx % (BN / 8);
      *(u16x8*)(C16 + (m0 + h * 128 + row) * (size_t)ldc + n0 + c8 * 8) =
          *(const u16x8*)(SH + row * STR + c8 * 8);
    }
  }
}

// named wrappers
// z=0: w2T = Wk . WqsT ; z=1: wvoT = woT . WvT  (adjacent 512KB-strided buffers)
__global__ __launch_bounds__(512, 2)
void ww_gemm(const uint16_t* A, const uint16_t* Bt, void* C) {
  gemm8_body<128, 0>(A, Bt, nullptr, C, nullptr, 512, 512, 512, 512, 512, 512,
                     262144, 262144, 262144, 0, 0);
}
__global__ __launch_bounds__(512, 2)
void yv_gemm(const uint16_t* A, const uint16_t* Bt, const float* bias, void* C) {
  gemm8_body<256, 0>(A, Bt, bias, C, nullptr, 16384, 1024, 512, 512, 512, 1024,
                     0, 0, 0, 0, 0);
}
// P' = exp(Y @ X^T + c_col) -> bf16, + row-sum partials
__global__ __launch_bounds__(512, 2)
void scores_gemm(const uint16_t* Y, const uint16_t* X, const float* cvec,
                 void* S, float* sums) {
  gemm8_body<256, 2>(Y, X, cvec, S, sums, 4096, 4096, 512, 1024, 512, 4096,
                     (long long)4096 * 1024, (long long)4096 * 512,
                     (long long)4096 * 4096, (long long)4096 * 64, 4096);
}
// out = (P' @ VW^T) * inv[row] + bo   (f32, final)
__global__ __launch_bounds__(512, 2)
void pvo_gemm(const uint16_t* A, const uint16_t* Bt, const float* bias,
              void* C, const float* inv) {
  gemm8_body<128, 4>(A, Bt, bias, C, inv, 4096, 512, 4096, 4096, 4096, 512,
                     (long long)4096 * 4096, (long long)512 * 4096,
                     (long long)4096 * 512, 4096, 0);
}

// inv[r] = 1 / sum_{c<64} partials[r][c]
__global__ __launch_bounds__(256)
void reduce_sums(const float* __restrict__ P, float* __restrict__ inv, int rows) {
  int r = blockIdx.x * 256 + threadIdx.x;
  if (r >= rows) return;
  const float4* p4 = (const float4*)(P + (size_t)r * 64);
  float s = 0.f;
  #pragma unroll
  for (int i = 0; i < 16; ++i) { float4 v = p4[i]; s += (v.x + v.y) + (v.z + v.w); }
  inv[r] = 1.f / s;
}

// ---------------- launch ----------------

extern "C" void kernel_launch(void* const* d_in, const int* in_sizes, int n_in,
                              void* d_out, int out_size, void* d_ws, size_t ws_size,
                              hipStream_t stream) {
  const float* x   = (const float*)d_in[0];
  const float* Wq  = (const float*)d_in[1];
  const float* bq  = (const float*)d_in[2];
  const float* Wk  = (const float*)d_in[3];
  const float* bk  = (const float*)d_in[4];
  const float* Wv  = (const float*)d_in[5];
  const float* bvp = (const float*)d_in[6];
  const float* Wo  = (const float*)d_in[7];
  const float* bo  = (const float*)d_in[8];
  float* out = (float*)d_out;

  char* ws = (char*)d_ws;
  const size_t MB = (size_t)1 << 20;
  const size_t HK = 512 * 1024;
  uint16_t* xb   = (uint16_t*)(ws);                // 16 MB
  uint16_t* yv   = (uint16_t*)(ws + 16 * MB);      // 32 MB (y | VW)
  uint16_t* Vt   = (uint16_t*)(ws + 48 * MB);      // 16 MB (VW^T)
  uint16_t* wkr  = (uint16_t*)(ws + 80 * MB);      // 0.5 MB  (ww A, z=0)
  uint16_t* woT  = (uint16_t*)(ws + 80 * MB + HK); // 0.5 MB  (ww A, z=1)
  uint16_t* wqs  = (uint16_t*)(ws + 81 * MB);      // 0.5 MB  (ww B, z=0)
  uint16_t* wvr  = (uint16_t*)(ws + 81 * MB + HK); // 0.5 MB  (ww B, z=1)
  uint16_t* yvW  = (uint16_t*)(ws + 82 * MB);      // 1 MB: w2T (z=0) | wvoT (z=1)
  float*    byv  = (float*)   (ws + 83 * MB);      // 4 KB (0 | bvo)
  float*    g    = (float*)   (ws + 83 * MB + 8 * 1024);  // 513 f32
  float*    sums = (float*)   (ws + 84 * MB);      // 4 MB
  float*    invs = (float*)   (ws + 88 * MB);      // 64 KB
  float*    cv   = (float*)   (ws + 89 * MB);      // 64 KB
  uint16_t* Sbuf = (uint16_t*)(ws + 96 * MB);      // nz*32 MB

  const int big = (ws_size >= 225 * MB);

  convert_x<<<dim3(4096), dim3(256), 0, stream>>>(x, xb);
  pack_wraw<<<dim3(128, 3), dim3(256), 0, stream>>>(Wq, Wk, Wv, wqs, wkr, wvr);
  pack_wo<<<dim3(8, 8), dim3(256), 0, stream>>>(Wo, woT);
  gemv_all<<<dim3(16, 3), dim3(256), 0, stream>>>(Wk, bq, bk, woT, bvp, g, byv);

  // z=0: w2T[n][m] = sum_d Wk[n][d]*(Wq s)[m][d] ; z=1: wvoT[n][d] = sum_k woT[n][k]*Wv[d][k]
  ww_gemm<<<dim3(8, 1, 2), dim3(512), 0, stream>>>(wkr, wqs, yvW);

  // yv = xb @ [w2T; wvoT]^T + [0; bvo]  -> [16384][1024] bf16 (y | VW)
  yv_gemm<<<dim3(256, 1, 1), dim3(512), 0, stream>>>(xb, yvW, byv, yv);

  transpose_v<<<dim3(64, 8, 4), dim3(256), 0, stream>>>(yv, Vt);
  c_vec<<<dim3(512), dim3(256), 0, stream>>>(xb, g, cv);

  if (big) {
    // single z=4 scores + single fused PV+output
    scores_gemm<<<dim3(256, 1, 4), dim3(512), 0, stream>>>(yv, xb, cv, Sbuf, sums);
    reduce_sums<<<dim3(64), dim3(256), 0, stream>>>(sums, invs, 4 * 4096);
    pvo_gemm<<<dim3(64, 1, 4), dim3(512), 0, stream>>>(Sbuf, Vt, bo, out, invs);
  } else {
    for (int p = 0; p < 2; ++p) {
      scores_gemm<<<dim3(256, 1, 2), dim3(512), 0, stream>>>(
          yv + (size_t)p * 2 * 4096 * 1024, xb + (size_t)p * 2 * 4096 * 512,
          cv + (size_t)p * 2 * 4096, Sbuf,
          sums + (size_t)p * 2 * 4096 * 64);
      reduce_sums<<<dim3(32), dim3(256), 0, stream>>>(
          sums + (size_t)p * 2 * 4096 * 64, invs + (size_t)p * 2 * 4096, 2 * 4096);
      pvo_gemm<<<dim3(64, 1, 2), dim3(512), 0, stream>>>(
          Sbuf, Vt + (size_t)p * 2 * 512 * 4096, bo,
          out + (size_t)p * 2 * 4096 * 512, invs + (size_t)p * 2 * 4096);
    }
  }
}